// Round 19
// baseline (299.084 us; speedup 1.0000x reference)
//
#include <hip/hip_runtime.h>

#define DI __device__ __forceinline__

typedef __attribute__((ext_vector_type(8))) short short8v;
typedef __attribute__((ext_vector_type(4))) float f32x4;

static constexpr int B_ = 4, S_ = 2048, D_ = 1024, H_ = 16, HD_ = 64;
static constexpr int M_ = B_ * S_;  // 8192 rows

// f32 -> bf16 round-nearest-even
DI unsigned short f2bf(float f) {
  unsigned u = __builtin_bit_cast(unsigned, f);
  u = (u + 0x7fffu + ((u >> 16) & 1u)) >> 16;
  return (unsigned short)u;
}

DI unsigned cvt_pk_bf16(float lo, float hi) {
  unsigned r;
  asm("v_cvt_pk_bf16_f32 %0, %1, %2" : "=v"(r) : "v"(lo), "v"(hi));
  return r;
}

// async global->LDS, 16B per lane; LDS dest must be wave-uniform base (HW adds lane*16)
DI void async_copy16(const void* g, void* l) {
  __builtin_amdgcn_global_load_lds((const __attribute__((address_space(1))) void*)g,
                                   (__attribute__((address_space(3))) void*)l, 16, 0, 0);
}

// ---------------- merged elementwise cast f32 -> bf16 (z selects q/k/v) ----------------
__global__ __launch_bounds__(256) void cast3_bf16_kernel(const float* __restrict__ q,
                                                         const float* __restrict__ k,
                                                         const float* __restrict__ v,
                                                         unsigned short* __restrict__ oq,
                                                         unsigned short* __restrict__ ok,
                                                         unsigned short* __restrict__ ov,
                                                         int n4) {
  const float* in = (blockIdx.z == 0) ? q : (blockIdx.z == 1) ? k : v;
  unsigned short* out = (blockIdx.z == 0) ? oq : (blockIdx.z == 1) ? ok : ov;
  int i = blockIdx.x * blockDim.x + threadIdx.x;
  int stride = gridDim.x * blockDim.x;
  for (; i < n4; i += stride) {
    float4 val = reinterpret_cast<const float4*>(in)[i];
    ushort4 o;
    o.x = f2bf(val.x); o.y = f2bf(val.y); o.z = f2bf(val.z); o.w = f2bf(val.w);
    reinterpret_cast<ushort4*>(out)[i] = o;
  }
}

// ---------------- merged transpose + cast weights: z selects Wq/Wk/Wv/Wo ----------------
__global__ __launch_bounds__(256) void transpose_cast4_kernel(const float* __restrict__ W0,
                                                              const float* __restrict__ W1,
                                                              const float* __restrict__ W2,
                                                              const float* __restrict__ W3,
                                                              unsigned short* __restrict__ T0,
                                                              unsigned short* __restrict__ T1,
                                                              unsigned short* __restrict__ T2,
                                                              unsigned short* __restrict__ T3,
                                                              int n) {
  const float* W = (blockIdx.z == 0) ? W0 : (blockIdx.z == 1) ? W1 : (blockIdx.z == 2) ? W2 : W3;
  unsigned short* Wt = (blockIdx.z == 0) ? T0 : (blockIdx.z == 1) ? T1 : (blockIdx.z == 2) ? T2 : T3;
  __shared__ float t[32][33];
  int bx = blockIdx.x * 32, by = blockIdx.y * 32;
  int x = threadIdx.x, y0 = threadIdx.y;
#pragma unroll
  for (int yy = 0; yy < 32; yy += 8)
    t[y0 + yy][x] = W[(long)(by + y0 + yy) * n + bx + x];
  __syncthreads();
#pragma unroll
  for (int yy = 0; yy < 32; yy += 8)
    Wt[(long)(bx + y0 + yy) * n + by + x] = f2bf(t[x][y0 + yy]);
}

// ---------------- pack mask (0/1 f32) into bit words, layout [B][S/64 kt][S q] ----------------
// NOTE: MBITS overlays XK; this kernel must run AFTER gemm_qkv has consumed XK.
__global__ __launch_bounds__(256) void pack_mask_kernel(const float* __restrict__ mask,
                                                        unsigned long long* __restrict__ bits,
                                                        int nwords) {
  int lane = threadIdx.x & 63;
  int wpb = blockDim.x >> 6;
  int w = blockIdx.x * wpb + (threadIdx.x >> 6);
  int stride = gridDim.x * wpb;
  for (; w < nwords; w += stride) {
    float v = mask[(long)w * 64 + lane];
    unsigned long long b = __ballot(v > 0.5f);
    if (lane == 0) {
      int bb = w >> 16, q = (w >> 5) & 2047, kt64 = w & 31;
      bits[((long)bb << 16) | (kt64 << 11) | q] = b;
    }
  }
}

// ---------------- GEMM core (round-12 PASSED): triple-buffered, depth-2 prefetch ----------------
// mode 0: bf16 out [M,N], val=(acc+bias)*scale
// mode 1: bf16 out as per-head transposed V with key-permuted columns (round-3 note)
// mode 2: f32 out [M,N]
DI void gemm_core(const unsigned short* __restrict__ A,
                  const unsigned short* __restrict__ Bt,
                  const float* __restrict__ bias,
                  void* __restrict__ out,
                  int Ndim, int Kdim, float scale, int mode,
                  unsigned short (*As)[128 * 32], unsigned short (*Bs)[128 * 32],
                  int bm, int bn) {
  const int tid = threadIdx.x;
  const int lane = tid & 63;
  const int w = tid >> 6;
  const int g = lane >> 4;
  const int l15 = lane & 15;
  const int wr = w >> 1, wc = w & 1;

  f32x4 zero = {0.f, 0.f, 0.f, 0.f};
  f32x4 acc[4][4];
#pragma unroll
  for (int i = 0; i < 4; ++i)
#pragma unroll
    for (int j = 0; j < 4; ++j) acc[i][j] = zero;

  const int srow = lane >> 2;        // 0..15 within 16-row chunk
  const int scol = (lane & 3) * 8;   // bf16 col offset, 8 elems = 16B

  auto stageg = [&](int k0, int bi) {
#pragma unroll
    for (int i = 0; i < 2; ++i) {
      int q = w * 2 + i;             // 1KB chunk index, rows [q*16, q*16+16)
      int row = q * 16 + srow;
      async_copy16(&A[(long)(bm + row) * Kdim + k0 + scol], &As[bi][q * 512]);
      async_copy16(&Bt[(long)(bn + row) * Kdim + k0 + scol], &Bs[bi][q * 512]);
    }
  };

  const int NT = Kdim / 32;
  stageg(0, 0);
  stageg(32, 1);
  asm volatile("s_waitcnt vmcnt(4)" ::: "memory");
  __builtin_amdgcn_sched_barrier(0);
  __builtin_amdgcn_s_barrier();
  asm volatile("" ::: "memory");

  for (int t = 0; t < NT; ++t) {
    if (t + 2 < NT) stageg((t + 2) * 32, (t + 2) % 3);

    const unsigned short* Ab = &As[t % 3][0];
    const unsigned short* Bb = &Bs[t % 3][0];
    short8v a[4], b[4];
#pragma unroll
    for (int i = 0; i < 4; ++i)
      a[i] = *reinterpret_cast<const short8v*>(&Ab[(wr * 64 + i * 16 + l15) * 32 + g * 8]);
#pragma unroll
    for (int j = 0; j < 4; ++j)
      b[j] = *reinterpret_cast<const short8v*>(&Bb[(wc * 64 + j * 16 + l15) * 32 + g * 8]);
#pragma unroll
    for (int i = 0; i < 4; ++i)
#pragma unroll
      for (int j = 0; j < 4; ++j)
        acc[i][j] = __builtin_amdgcn_mfma_f32_16x16x32_bf16(a[i], b[j], acc[i][j], 0, 0, 0);

    if (t + 2 < NT) {
      asm volatile("s_waitcnt vmcnt(4) lgkmcnt(0)" ::: "memory");
    } else {
      asm volatile("s_waitcnt vmcnt(0) lgkmcnt(0)" ::: "memory");
    }
    __builtin_amdgcn_sched_barrier(0);
    __builtin_amdgcn_s_barrier();
    asm volatile("" ::: "memory");
  }

#pragma unroll
  for (int jj = 0; jj < 4; ++jj) {
    int n = bn + wc * 64 + jj * 16 + l15;
    float bs = bias[n];
#pragma unroll
    for (int i = 0; i < 4; ++i) {
      int m0 = bm + wr * 64 + i * 16 + g * 4;  // rows m0..m0+3 (reg r)
      if (mode == 0) {
        unsigned short* o = (unsigned short*)out;
#pragma unroll
        for (int r = 0; r < 4; ++r)
          o[(long)(m0 + r) * Ndim + n] = f2bf((acc[i][jj][r] + bs) * scale);
      } else if (mode == 1) {
        int b2 = m0 >> 11, s0 = m0 & 2047;
        int s0p = (s0 & ~31) | (((s0 >> 2) & 3) << 3) | (((s0 >> 4) & 1) << 2);
        int h2 = n >> 6, d2 = n & 63;
        unsigned short* o = (unsigned short*)out;
        ushort4 v;
        v.x = f2bf(acc[i][jj][0] + bs);
        v.y = f2bf(acc[i][jj][1] + bs);
        v.z = f2bf(acc[i][jj][2] + bs);
        v.w = f2bf(acc[i][jj][3] + bs);
        *reinterpret_cast<ushort4*>(&o[((long)((b2 * 16 + h2) * 64 + d2) << 11) + s0p]) = v;
      } else {
        float* o = (float*)out;
#pragma unroll
        for (int r = 0; r < 4; ++r)
          o[(long)(m0 + r) * Ndim + n] = acc[i][jj][r] + bs;
      }
    }
  }
}

// merged Q/K/V projection GEMM: blockIdx.z selects operands; 1536 blocks pack CU tails
__global__ __launch_bounds__(256) void gemm_qkv_kernel(const unsigned short* __restrict__ XQ,
                                                       const unsigned short* __restrict__ XK,
                                                       const unsigned short* __restrict__ XV,
                                                       const unsigned short* __restrict__ WQT,
                                                       const unsigned short* __restrict__ WKT,
                                                       const unsigned short* __restrict__ WVT,
                                                       const float* __restrict__ bq,
                                                       const float* __restrict__ bk,
                                                       const float* __restrict__ bv,
                                                       unsigned short* __restrict__ QB,
                                                       unsigned short* __restrict__ KB,
                                                       unsigned short* __restrict__ VT,
                                                       float qscale) {
  __shared__ unsigned short As[3][128 * 32];
  __shared__ unsigned short Bs[3][128 * 32];
  const int z = blockIdx.z;
  const unsigned short* A  = (z == 0) ? XQ : (z == 1) ? XK : XV;
  const unsigned short* Bt = (z == 0) ? WQT : (z == 1) ? WKT : WVT;
  const float* bias        = (z == 0) ? bq : (z == 1) ? bk : bv;
  void* out                = (z == 0) ? (void*)QB : (z == 1) ? (void*)KB : (void*)VT;
  float scale              = (z == 0) ? qscale : 1.f;
  int mode                 = (z == 2) ? 1 : 0;
  gemm_core(A, Bt, bias, out, D_, D_, scale, mode, As, Bs,
            blockIdx.x * 128, blockIdx.y * 128);
}

// output GEMM (mode 2, f32 out)
__global__ __launch_bounds__(256) void gemm_out_kernel(const unsigned short* __restrict__ A,
                                                       const unsigned short* __restrict__ Bt,
                                                       const float* __restrict__ bias,
                                                       float* __restrict__ out) {
  __shared__ unsigned short As[3][128 * 32];
  __shared__ unsigned short Bs[3][128 * 32];
  gemm_core(A, Bt, bias, out, D_, D_, 1.f, 2, As, Bs, blockIdx.x * 128, blockIdx.y * 128);
}

// ---------------- fused flash attention (round-18 + triple-buffer / one barrier per tile) ----------------
// XCD-aware bijective remap (r16) + defer-max (r17) + 32-bit mask & deferred l_run (r18).
// New: K/V LDS triple-buffered, ONE s_barrier per tile (mirrors the r12-PASSED GEMM v4
// pattern): a wave at most one barrier ahead issues stage(t+2) into buf[(t+2)%3] =
// buf[(t-1)%3], whose readers all finished during compute(t-1) (every ds_read is consumed
// by an MFMA within its own iteration). vmcnt accounting per-wave, unchanged: vmcnt(5) =
// own stage(t+1) 4 loads + mask(t+1) 1 load in flight.
__global__ __launch_bounds__(256, 3) void attn_kernel(const unsigned short* __restrict__ Q,   // [B,S,D] pre-scaled log2e/8
                                                      const unsigned short* __restrict__ Kb,  // [B,S,D]
                                                      const unsigned short* __restrict__ Vt,  // [B*H,64,S] key-permuted
                                                      const unsigned long long* __restrict__ mbits, // [B][32][2048]
                                                      unsigned short* __restrict__ attn) {    // [B,S,D]
  __shared__ unsigned short Ks[3][64 * 64];       // swizzled, rows = key
  __shared__ unsigned short Vs[3][64 * 64];       // swizzled, rows = d
  const int lane = threadIdx.x & 63;
  const int w = threadIdx.x >> 6;
  const int g = lane >> 4;
  const int l15 = lane & 15;
  const int linear = blockIdx.x + 32 * blockIdx.y;
  const int qt = (linear >> 3) & 31;
  const int bh = (linear & 7) + ((linear >> 8) << 3);
  const int b = bh >> 4, h = bh & 15;
  const int q0 = qt * 64 + w * 16 + l15;  // this wave's q row

  // Q fragment doubles as MFMA B-operand: col n=q=lane&15, k=d=g*8+j (+32)
  const unsigned short* qp = Q + ((long)b * S_ + q0) * D_ + h * HD_ + g * 8;
  short8v qf0 = *reinterpret_cast<const short8v*>(qp);
  short8v qf1 = *reinterpret_cast<const short8v*>(qp + 32);

  // staging: LDS chunk c holds global chunk c ^ (row&7)  (inverse-swizzled source)
  const int srow = lane >> 3;
  const int schunk = ((lane & 7) ^ (lane >> 3)) * 8;  // in elements
  const unsigned short* kstage = Kb + (long)b * S_ * D_ + h * HD_;
  const unsigned short* vstage = Vt + (long)bh * HD_ * S_;

  f32x4 zero = {0.f, 0.f, 0.f, 0.f};
  f32x4 oacc[4] = {zero, zero, zero, zero};
  float m_run = -1e30f, l_run = 0.f;  // l_run = per-lane partial (reduced in epilogue)

  const unsigned long long* mbase = mbits + ((long)b << 16);
  const int swz = l15 & 7;

  auto stage = [&](int kt, int bi) {
#pragma unroll
    for (int i = 0; i < 2; ++i) {
      int blk8 = w * 2 + i;
      async_copy16(&kstage[(long)(kt + blk8 * 8 + srow) * D_ + schunk], &Ks[bi][blk8 * 512]);
      async_copy16(&vstage[(long)(blk8 * 8 + srow) * S_ + kt + schunk], &Vs[bi][blk8 * 512]);
    }
  };

  // prologue: mask(0) + stage(0) -> buf 0
  unsigned long long mw_cur = mbase[q0];
  stage(0, 0);

  const int NT = S_ / 64;
  for (int t = 0; t < NT; ++t) {
    unsigned long long mw_nxt = 0;
    if (t < NT - 1) {
      // prefetch next tile: 1 mask word + 4 stage loads into buf[(t+1)%3], counted wait.
      mw_nxt = mbase[((t + 1) << 11) + q0];
      stage((t + 1) * 64, (t + 1) % 3);
      asm volatile("s_waitcnt vmcnt(5)" ::: "memory");
    } else {
      asm volatile("s_waitcnt vmcnt(0)" ::: "memory");
    }
    __builtin_amdgcn_s_barrier();
    asm volatile("" ::: "memory");

    const unsigned short* Kbuf = &Ks[t % 3][0];
    const unsigned short* Vbuf = &Vs[t % 3][0];

    // ---- QK^T (transposed): acc col = q = lane&15, row = key ----
    f32x4 lt[4];
    __builtin_amdgcn_s_setprio(1);
#pragma unroll
    for (int g2 = 0; g2 < 4; ++g2) {
      const unsigned short* kr = &Kbuf[(g2 * 16 + l15) * 64];
      short8v kf0 = *reinterpret_cast<const short8v*>(&kr[(g ^ swz) * 8]);
      short8v kf1 = *reinterpret_cast<const short8v*>(&kr[((g + 4) ^ swz) * 8]);
      f32x4 c = zero;
      c = __builtin_amdgcn_mfma_f32_16x16x32_bf16(kf0, qf0, c, 0, 0, 0);
      c = __builtin_amdgcn_mfma_f32_16x16x32_bf16(kf1, qf1, c, 0, 0, 0);
      lt[g2] = c;
    }
    __builtin_amdgcn_s_setprio(0);

    // ---- online softmax (-1e30 inject via 32-bit extracted words; defer-max) ----
    unsigned mlo = (unsigned)(mw_cur >> (g * 4));          // bits for g2=0,1 at (g2)*16+r
    unsigned mhi = (unsigned)((mw_cur >> 32) >> (g * 4));  // bits for g2=2,3 at (g2&1)*16+r
    float tmax = -1e30f;
#pragma unroll
    for (int g2 = 0; g2 < 4; ++g2) {
      unsigned word = (g2 < 2) ? mlo : mhi;
#pragma unroll
      for (int r = 0; r < 4; ++r) {
        float v = ((word >> ((g2 & 1) * 16 + r)) & 1u) ? -1e30f : lt[g2][r];
        lt[g2][r] = v;
        tmax = fmaxf(tmax, v);
      }
    }
    tmax = fmaxf(tmax, __shfl_xor(tmax, 16));
    tmax = fmaxf(tmax, __shfl_xor(tmax, 32));
    // defer-max (T13, THR=8): only rescale when some q-row's tile max outgrew m_run+8.
    if (!__all(tmax <= m_run + 8.f)) {
      float m_new = fmaxf(m_run, tmax);
      float alpha = __builtin_amdgcn_exp2f(m_run - m_new);  // q-uniform across g-lanes
      l_run *= alpha;
#pragma unroll
      for (int d = 0; d < 4; ++d) oacc[d] *= alpha;
      m_run = m_new;
    }
    float p[4][4];
    float tsum = 0.f;
#pragma unroll
    for (int g2 = 0; g2 < 4; ++g2)
#pragma unroll
      for (int r = 0; r < 4; ++r) {
        p[g2][r] = __builtin_amdgcn_exp2f(lt[g2][r] - m_run);
        tsum += p[g2][r];
      }
    l_run += tsum;  // per-lane partial; cross-lane reduce deferred to epilogue
    // pack P^T B-fragment in-register: pfr[s][j] = p[2s + (j>>2)][j&3]
    short8v pfr[2];
#pragma unroll
    for (int s = 0; s < 2; ++s) {
      union { unsigned u[4]; short8v v; } pu;
      pu.u[0] = cvt_pk_bf16(p[2 * s][0], p[2 * s][1]);
      pu.u[1] = cvt_pk_bf16(p[2 * s][2], p[2 * s][3]);
      pu.u[2] = cvt_pk_bf16(p[2 * s + 1][0], p[2 * s + 1][1]);
      pu.u[3] = cvt_pk_bf16(p[2 * s + 1][2], p[2 * s + 1][3]);
      pfr[s] = pu.v;
    }

    // ---- PV: O^T += V^T * P^T ----
    __builtin_amdgcn_s_setprio(1);
#pragma unroll
    for (int d0 = 0; d0 < 4; ++d0) {
      const unsigned short* vr = &Vbuf[(d0 * 16 + l15) * 64];
#pragma unroll
      for (int s = 0; s < 2; ++s) {
        short8v vf = *reinterpret_cast<const short8v*>(&vr[((s * 4 + g) ^ swz) * 8]);
        oacc[d0] = __builtin_amdgcn_mfma_f32_16x16x32_bf16(vf, pfr[s], oacc[d0], 0, 0, 0);
      }
    }
    __builtin_amdgcn_s_setprio(0);

    mw_cur = mw_nxt;
  }

  // epilogue: reduce the per-lane l_run partials across the 4 g-lanes of this q
  l_run += __shfl_xor(l_run, 16);
  l_run += __shfl_xor(l_run, 32);
  float inv = 1.f / l_run;
#pragma unroll
  for (int d0 = 0; d0 < 4; ++d0) {
    ushort4 o;
    o.x = f2bf(oacc[d0][0] * inv);
    o.y = f2bf(oacc[d0][1] * inv);
    o.z = f2bf(oacc[d0][2] * inv);
    o.w = f2bf(oacc[d0][3] * inv);
    *reinterpret_cast<ushort4*>(&attn[((long)b * S_ + q0) * D_ + h * HD_ + d0 * 16 + g * 4]) = o;
  }
}

// ---------------- launch (round-16 order: pack_mask AFTER gemm_qkv -- MBITS overlays XK) ----------------
extern "C" void kernel_launch(void* const* d_in, const int* in_sizes, int n_in,
                              void* d_out, int out_size, void* d_ws, size_t ws_size,
                              hipStream_t stream) {
  const float* query = (const float*)d_in[0];
  const float* key   = (const float*)d_in[1];
  const float* value = (const float*)d_in[2];
  const float* mask  = (const float*)d_in[3];
  const float* Wq = (const float*)d_in[4];
  const float* bq = (const float*)d_in[5];
  const float* Wk = (const float*)d_in[6];
  const float* bk = (const float*)d_in[7];
  const float* Wv = (const float*)d_in[8];
  const float* bv = (const float*)d_in[9];
  const float* Wo = (const float*)d_in[10];
  const float* bo = (const float*)d_in[11];

  char* ws = (char*)d_ws;
  unsigned short* XQ  = (unsigned short*)(ws);
  unsigned short* XK  = (unsigned short*)(ws + (16ull << 20));
  unsigned short* XV  = (unsigned short*)(ws + (32ull << 20));
  unsigned short* WQT = (unsigned short*)(ws + (48ull << 20));
  unsigned short* WKT = (unsigned short*)(ws + (50ull << 20));
  unsigned short* WVT = (unsigned short*)(ws + (52ull << 20));
  unsigned short* WOT = (unsigned short*)(ws + (54ull << 20));
  unsigned short* QB  = (unsigned short*)(ws + (56ull << 20));
  unsigned short* KB  = (unsigned short*)(ws + (72ull << 20));
  unsigned short* VT  = (unsigned short*)(ws + (88ull << 20));
  unsigned long long* MBITS = (unsigned long long*)(ws + (16ull << 20));  // overlays XK (dead post-gemm_qkv)
  unsigned short* ATTN = XQ;                                              // overlays XQ (dead post-gemm_qkv)

  const int n4 = M_ * D_ / 4;
  dim3 cg(2048, 1, 3);
  cast3_bf16_kernel<<<cg, 256, 0, stream>>>(query, key, value, XQ, XK, XV, n4);

  dim3 tg(D_ / 32, D_ / 32, 4), tb(32, 8);
  transpose_cast4_kernel<<<tg, tb, 0, stream>>>(Wq, Wk, Wv, Wo, WQT, WKT, WVT, WOT, D_);

  // Q prescale: 1/sqrt(HD) * log2(e) so softmax runs in exp2 domain
  dim3 gq(M_ / 128, D_ / 128, 3);
  gemm_qkv_kernel<<<gq, 256, 0, stream>>>(XQ, XK, XV, WQT, WKT, WVT, bq, bk, bv,
                                          QB, KB, VT, 0.18033688011112042f);

  pack_mask_kernel<<<2048, 256, 0, stream>>>(mask, MBITS, B_ * S_ * S_ / 64);

  dim3 ag(S_ / 64, B_ * H_);
  attn_kernel<<<ag, 256, 0, stream>>>(QB, KB, VT, MBITS, ATTN);

  dim3 gg(M_ / 128, D_ / 128);
  gemm_out_kernel<<<gg, 256, 0, stream>>>(ATTN, WOT, bo, (float*)d_out);
}

// Round 20
// 279.798 us; speedup vs baseline: 1.0689x; 1.0689x over previous
//
#include <hip/hip_runtime.h>

#define DI __device__ __forceinline__

typedef __attribute__((ext_vector_type(8))) short short8v;
typedef __attribute__((ext_vector_type(4))) float f32x4;

static constexpr int B_ = 4, S_ = 2048, D_ = 1024, H_ = 16, HD_ = 64;
static constexpr int M_ = B_ * S_;  // 8192 rows

// f32 -> bf16 round-nearest-even
DI unsigned short f2bf(float f) {
  unsigned u = __builtin_bit_cast(unsigned, f);
  u = (u + 0x7fffu + ((u >> 16) & 1u)) >> 16;
  return (unsigned short)u;
}

DI unsigned cvt_pk_bf16(float lo, float hi) {
  unsigned r;
  asm("v_cvt_pk_bf16_f32 %0, %1, %2" : "=v"(r) : "v"(lo), "v"(hi));
  return r;
}

// async global->LDS, 16B per lane; LDS dest must be wave-uniform base (HW adds lane*16)
DI void async_copy16(const void* g, void* l) {
  __builtin_amdgcn_global_load_lds((const __attribute__((address_space(1))) void*)g,
                                   (__attribute__((address_space(3))) void*)l, 16, 0, 0);
}

// ---------------- merged elementwise cast f32 -> bf16 (z selects q/k/v) ----------------
__global__ __launch_bounds__(256) void cast3_bf16_kernel(const float* __restrict__ q,
                                                         const float* __restrict__ k,
                                                         const float* __restrict__ v,
                                                         unsigned short* __restrict__ oq,
                                                         unsigned short* __restrict__ ok,
                                                         unsigned short* __restrict__ ov,
                                                         int n4) {
  const float* in = (blockIdx.z == 0) ? q : (blockIdx.z == 1) ? k : v;
  unsigned short* out = (blockIdx.z == 0) ? oq : (blockIdx.z == 1) ? ok : ov;
  int i = blockIdx.x * blockDim.x + threadIdx.x;
  int stride = gridDim.x * blockDim.x;
  for (; i < n4; i += stride) {
    float4 val = reinterpret_cast<const float4*>(in)[i];
    ushort4 o;
    o.x = f2bf(val.x); o.y = f2bf(val.y); o.z = f2bf(val.z); o.w = f2bf(val.w);
    reinterpret_cast<ushort4*>(out)[i] = o;
  }
}

// ---------------- merged transpose + cast weights: z selects Wq/Wk/Wv/Wo ----------------
__global__ __launch_bounds__(256) void transpose_cast4_kernel(const float* __restrict__ W0,
                                                              const float* __restrict__ W1,
                                                              const float* __restrict__ W2,
                                                              const float* __restrict__ W3,
                                                              unsigned short* __restrict__ T0,
                                                              unsigned short* __restrict__ T1,
                                                              unsigned short* __restrict__ T2,
                                                              unsigned short* __restrict__ T3,
                                                              int n) {
  const float* W = (blockIdx.z == 0) ? W0 : (blockIdx.z == 1) ? W1 : (blockIdx.z == 2) ? W2 : W3;
  unsigned short* Wt = (blockIdx.z == 0) ? T0 : (blockIdx.z == 1) ? T1 : (blockIdx.z == 2) ? T2 : T3;
  __shared__ float t[32][33];
  int bx = blockIdx.x * 32, by = blockIdx.y * 32;
  int x = threadIdx.x, y0 = threadIdx.y;
#pragma unroll
  for (int yy = 0; yy < 32; yy += 8)
    t[y0 + yy][x] = W[(long)(by + y0 + yy) * n + bx + x];
  __syncthreads();
#pragma unroll
  for (int yy = 0; yy < 32; yy += 8)
    Wt[(long)(bx + y0 + yy) * n + by + x] = f2bf(t[x][y0 + yy]);
}

// ---------------- pack mask (0/1 f32) into bit words, layout [B][S/64 kt][S q] ----------------
// NOTE: MBITS overlays XK; this kernel must run AFTER gemm_qkv has consumed XK.
__global__ __launch_bounds__(256) void pack_mask_kernel(const float* __restrict__ mask,
                                                        unsigned long long* __restrict__ bits,
                                                        int nwords) {
  int lane = threadIdx.x & 63;
  int wpb = blockDim.x >> 6;
  int w = blockIdx.x * wpb + (threadIdx.x >> 6);
  int stride = gridDim.x * wpb;
  for (; w < nwords; w += stride) {
    float v = mask[(long)w * 64 + lane];
    unsigned long long b = __ballot(v > 0.5f);
    if (lane == 0) {
      int bb = w >> 16, q = (w >> 5) & 2047, kt64 = w & 31;
      bits[((long)bb << 16) | (kt64 << 11) | q] = b;
    }
  }
}

// ---------------- GEMM core (round-12 PASSED): triple-buffered, depth-2 prefetch ----------------
// mode 0: bf16 out [M,N], val=(acc+bias)*scale
// mode 1: bf16 out as per-head transposed V with key-permuted columns (round-3 note)
// mode 2: f32 out [M,N]
DI void gemm_core(const unsigned short* __restrict__ A,
                  const unsigned short* __restrict__ Bt,
                  const float* __restrict__ bias,
                  void* __restrict__ out,
                  int Ndim, int Kdim, float scale, int mode,
                  unsigned short (*As)[128 * 32], unsigned short (*Bs)[128 * 32],
                  int bm, int bn) {
  const int tid = threadIdx.x;
  const int lane = tid & 63;
  const int w = tid >> 6;
  const int g = lane >> 4;
  const int l15 = lane & 15;
  const int wr = w >> 1, wc = w & 1;

  f32x4 zero = {0.f, 0.f, 0.f, 0.f};
  f32x4 acc[4][4];
#pragma unroll
  for (int i = 0; i < 4; ++i)
#pragma unroll
    for (int j = 0; j < 4; ++j) acc[i][j] = zero;

  const int srow = lane >> 2;        // 0..15 within 16-row chunk
  const int scol = (lane & 3) * 8;   // bf16 col offset, 8 elems = 16B

  auto stageg = [&](int k0, int bi) {
#pragma unroll
    for (int i = 0; i < 2; ++i) {
      int q = w * 2 + i;             // 1KB chunk index, rows [q*16, q*16+16)
      int row = q * 16 + srow;
      async_copy16(&A[(long)(bm + row) * Kdim + k0 + scol], &As[bi][q * 512]);
      async_copy16(&Bt[(long)(bn + row) * Kdim + k0 + scol], &Bs[bi][q * 512]);
    }
  };

  const int NT = Kdim / 32;
  stageg(0, 0);
  stageg(32, 1);
  asm volatile("s_waitcnt vmcnt(4)" ::: "memory");
  __builtin_amdgcn_sched_barrier(0);
  __builtin_amdgcn_s_barrier();
  asm volatile("" ::: "memory");

  for (int t = 0; t < NT; ++t) {
    if (t + 2 < NT) stageg((t + 2) * 32, (t + 2) % 3);

    const unsigned short* Ab = &As[t % 3][0];
    const unsigned short* Bb = &Bs[t % 3][0];
    short8v a[4], b[4];
#pragma unroll
    for (int i = 0; i < 4; ++i)
      a[i] = *reinterpret_cast<const short8v*>(&Ab[(wr * 64 + i * 16 + l15) * 32 + g * 8]);
#pragma unroll
    for (int j = 0; j < 4; ++j)
      b[j] = *reinterpret_cast<const short8v*>(&Bb[(wc * 64 + j * 16 + l15) * 32 + g * 8]);
#pragma unroll
    for (int i = 0; i < 4; ++i)
#pragma unroll
      for (int j = 0; j < 4; ++j)
        acc[i][j] = __builtin_amdgcn_mfma_f32_16x16x32_bf16(a[i], b[j], acc[i][j], 0, 0, 0);

    if (t + 2 < NT) {
      asm volatile("s_waitcnt vmcnt(4) lgkmcnt(0)" ::: "memory");
    } else {
      asm volatile("s_waitcnt vmcnt(0) lgkmcnt(0)" ::: "memory");
    }
    __builtin_amdgcn_sched_barrier(0);
    __builtin_amdgcn_s_barrier();
    asm volatile("" ::: "memory");
  }

#pragma unroll
  for (int jj = 0; jj < 4; ++jj) {
    int n = bn + wc * 64 + jj * 16 + l15;
    float bs = bias[n];
#pragma unroll
    for (int i = 0; i < 4; ++i) {
      int m0 = bm + wr * 64 + i * 16 + g * 4;  // rows m0..m0+3 (reg r)
      if (mode == 0) {
        unsigned short* o = (unsigned short*)out;
#pragma unroll
        for (int r = 0; r < 4; ++r)
          o[(long)(m0 + r) * Ndim + n] = f2bf((acc[i][jj][r] + bs) * scale);
      } else if (mode == 1) {
        int b2 = m0 >> 11, s0 = m0 & 2047;
        int s0p = (s0 & ~31) | (((s0 >> 2) & 3) << 3) | (((s0 >> 4) & 1) << 2);
        int h2 = n >> 6, d2 = n & 63;
        unsigned short* o = (unsigned short*)out;
        ushort4 v;
        v.x = f2bf(acc[i][jj][0] + bs);
        v.y = f2bf(acc[i][jj][1] + bs);
        v.z = f2bf(acc[i][jj][2] + bs);
        v.w = f2bf(acc[i][jj][3] + bs);
        *reinterpret_cast<ushort4*>(&o[((long)((b2 * 16 + h2) * 64 + d2) << 11) + s0p]) = v;
      } else {
        float* o = (float*)out;
#pragma unroll
        for (int r = 0; r < 4; ++r)
          o[(long)(m0 + r) * Ndim + n] = acc[i][jj][r] + bs;
      }
    }
  }
}

// merged Q/K/V projection GEMM: blockIdx.z selects operands; 1536 blocks pack CU tails
__global__ __launch_bounds__(256) void gemm_qkv_kernel(const unsigned short* __restrict__ XQ,
                                                       const unsigned short* __restrict__ XK,
                                                       const unsigned short* __restrict__ XV,
                                                       const unsigned short* __restrict__ WQT,
                                                       const unsigned short* __restrict__ WKT,
                                                       const unsigned short* __restrict__ WVT,
                                                       const float* __restrict__ bq,
                                                       const float* __restrict__ bk,
                                                       const float* __restrict__ bv,
                                                       unsigned short* __restrict__ QB,
                                                       unsigned short* __restrict__ KB,
                                                       unsigned short* __restrict__ VT,
                                                       float qscale) {
  __shared__ unsigned short As[3][128 * 32];
  __shared__ unsigned short Bs[3][128 * 32];
  const int z = blockIdx.z;
  const unsigned short* A  = (z == 0) ? XQ : (z == 1) ? XK : XV;
  const unsigned short* Bt = (z == 0) ? WQT : (z == 1) ? WKT : WVT;
  const float* bias        = (z == 0) ? bq : (z == 1) ? bk : bv;
  void* out                = (z == 0) ? (void*)QB : (z == 1) ? (void*)KB : (void*)VT;
  float scale              = (z == 0) ? qscale : 1.f;
  int mode                 = (z == 2) ? 1 : 0;
  gemm_core(A, Bt, bias, out, D_, D_, scale, mode, As, Bs,
            blockIdx.x * 128, blockIdx.y * 128);
}

// output GEMM (mode 2, f32 out)
__global__ __launch_bounds__(256) void gemm_out_kernel(const unsigned short* __restrict__ A,
                                                       const unsigned short* __restrict__ Bt,
                                                       const float* __restrict__ bias,
                                                       float* __restrict__ out) {
  __shared__ unsigned short As[3][128 * 32];
  __shared__ unsigned short Bs[3][128 * 32];
  gemm_core(A, Bt, bias, out, D_, D_, 1.f, 2, As, Bs, blockIdx.x * 128, blockIdx.y * 128);
}

// ---------------- fused flash attention (round-18 VERBATIM: best verified, 128.7us) ----------------
// XCD-aware bijective remap (r16) + defer-max (r17) + 32-bit mask extraction and
// deferred l_run reduction (r18). Double-buffered K/V, counted vmcnt(5), two barriers
// per tile (triple-buffer/one-barrier variant REGRESSED in r19: LDS 48KB cut occupancy,
// and unsynced stage traffic serialized against compute on the LDS port).
__global__ __launch_bounds__(256, 4) void attn_kernel(const unsigned short* __restrict__ Q,   // [B,S,D] pre-scaled log2e/8
                                                      const unsigned short* __restrict__ Kb,  // [B,S,D]
                                                      const unsigned short* __restrict__ Vt,  // [B*H,64,S] key-permuted
                                                      const unsigned long long* __restrict__ mbits, // [B][32][2048]
                                                      unsigned short* __restrict__ attn) {    // [B,S,D]
  __shared__ unsigned short Ks[2][64 * 64];       // swizzled, rows = key
  __shared__ unsigned short Vs[2][64 * 64];       // swizzled, rows = d
  const int lane = threadIdx.x & 63;
  const int w = threadIdx.x >> 6;
  const int g = lane >> 4;
  const int l15 = lane & 15;
  const int linear = blockIdx.x + 32 * blockIdx.y;
  const int qt = (linear >> 3) & 31;
  const int bh = (linear & 7) + ((linear >> 8) << 3);
  const int b = bh >> 4, h = bh & 15;
  const int q0 = qt * 64 + w * 16 + l15;  // this wave's q row

  // Q fragment doubles as MFMA B-operand: col n=q=lane&15, k=d=g*8+j (+32)
  const unsigned short* qp = Q + ((long)b * S_ + q0) * D_ + h * HD_ + g * 8;
  short8v qf0 = *reinterpret_cast<const short8v*>(qp);
  short8v qf1 = *reinterpret_cast<const short8v*>(qp + 32);

  // staging: LDS chunk c holds global chunk c ^ (row&7)  (inverse-swizzled source)
  const int srow = lane >> 3;
  const int schunk = ((lane & 7) ^ (lane >> 3)) * 8;  // in elements
  const unsigned short* kstage = Kb + (long)b * S_ * D_ + h * HD_;
  const unsigned short* vstage = Vt + (long)bh * HD_ * S_;

  f32x4 zero = {0.f, 0.f, 0.f, 0.f};
  f32x4 oacc[4] = {zero, zero, zero, zero};
  float m_run = -1e30f, l_run = 0.f;  // l_run = per-lane partial (reduced in epilogue)

  const unsigned long long* mbase = mbits + ((long)b << 16);
  const int swz = l15 & 7;

  auto stage = [&](int kt, int bi) {
#pragma unroll
    for (int i = 0; i < 2; ++i) {
      int blk8 = w * 2 + i;
      async_copy16(&kstage[(long)(kt + blk8 * 8 + srow) * D_ + schunk], &Ks[bi][blk8 * 512]);
      async_copy16(&vstage[(long)(blk8 * 8 + srow) * S_ + kt + schunk], &Vs[bi][blk8 * 512]);
    }
  };

  // prologue: mask(0) + stage(0) -> buf 0
  unsigned long long mw_cur = mbase[q0];
  stage(0, 0);

  int cur = 0;
  for (int t = 0; t < S_ / 64; ++t) {
    unsigned long long mw_nxt = 0;
    if (t < S_ / 64 - 1) {
      // prefetch next tile: 1 mask word + 4 stage loads, then counted wait.
      mw_nxt = mbase[((t + 1) << 11) + q0];
      stage((t + 1) * 64, cur ^ 1);
      asm volatile("s_waitcnt vmcnt(5)" ::: "memory");
    } else {
      asm volatile("s_waitcnt vmcnt(0)" ::: "memory");
    }
    __builtin_amdgcn_s_barrier();
    asm volatile("" ::: "memory");

    const unsigned short* Kbuf = &Ks[cur][0];
    const unsigned short* Vbuf = &Vs[cur][0];

    // ---- QK^T (transposed): acc col = q = lane&15, row = key ----
    f32x4 lt[4];
    __builtin_amdgcn_s_setprio(1);
#pragma unroll
    for (int g2 = 0; g2 < 4; ++g2) {
      const unsigned short* kr = &Kbuf[(g2 * 16 + l15) * 64];
      short8v kf0 = *reinterpret_cast<const short8v*>(&kr[(g ^ swz) * 8]);
      short8v kf1 = *reinterpret_cast<const short8v*>(&kr[((g + 4) ^ swz) * 8]);
      f32x4 c = zero;
      c = __builtin_amdgcn_mfma_f32_16x16x32_bf16(kf0, qf0, c, 0, 0, 0);
      c = __builtin_amdgcn_mfma_f32_16x16x32_bf16(kf1, qf1, c, 0, 0, 0);
      lt[g2] = c;
    }
    __builtin_amdgcn_s_setprio(0);

    // ---- online softmax (-1e30 inject via 32-bit extracted words; defer-max) ----
    unsigned mlo = (unsigned)(mw_cur >> (g * 4));          // bits for g2=0,1 at (g2)*16+r
    unsigned mhi = (unsigned)((mw_cur >> 32) >> (g * 4));  // bits for g2=2,3 at (g2&1)*16+r
    float tmax = -1e30f;
#pragma unroll
    for (int g2 = 0; g2 < 4; ++g2) {
      unsigned word = (g2 < 2) ? mlo : mhi;
#pragma unroll
      for (int r = 0; r < 4; ++r) {
        float v = ((word >> ((g2 & 1) * 16 + r)) & 1u) ? -1e30f : lt[g2][r];
        lt[g2][r] = v;
        tmax = fmaxf(tmax, v);
      }
    }
    tmax = fmaxf(tmax, __shfl_xor(tmax, 16));
    tmax = fmaxf(tmax, __shfl_xor(tmax, 32));
    // defer-max (T13, THR=8): only rescale when some q-row's tile max outgrew m_run+8.
    if (!__all(tmax <= m_run + 8.f)) {
      float m_new = fmaxf(m_run, tmax);
      float alpha = __builtin_amdgcn_exp2f(m_run - m_new);  // q-uniform across g-lanes
      l_run *= alpha;
#pragma unroll
      for (int d = 0; d < 4; ++d) oacc[d] *= alpha;
      m_run = m_new;
    }
    float p[4][4];
    float tsum = 0.f;
#pragma unroll
    for (int g2 = 0; g2 < 4; ++g2)
#pragma unroll
      for (int r = 0; r < 4; ++r) {
        p[g2][r] = __builtin_amdgcn_exp2f(lt[g2][r] - m_run);
        tsum += p[g2][r];
      }
    l_run += tsum;  // per-lane partial; cross-lane reduce deferred to epilogue
    // pack P^T B-fragment in-register: pfr[s][j] = p[2s + (j>>2)][j&3]
    short8v pfr[2];
#pragma unroll
    for (int s = 0; s < 2; ++s) {
      union { unsigned u[4]; short8v v; } pu;
      pu.u[0] = cvt_pk_bf16(p[2 * s][0], p[2 * s][1]);
      pu.u[1] = cvt_pk_bf16(p[2 * s][2], p[2 * s][3]);
      pu.u[2] = cvt_pk_bf16(p[2 * s + 1][0], p[2 * s + 1][1]);
      pu.u[3] = cvt_pk_bf16(p[2 * s + 1][2], p[2 * s + 1][3]);
      pfr[s] = pu.v;
    }

    // ---- PV: O^T += V^T * P^T ----
    __builtin_amdgcn_s_setprio(1);
#pragma unroll
    for (int d0 = 0; d0 < 4; ++d0) {
      const unsigned short* vr = &Vbuf[(d0 * 16 + l15) * 64];
#pragma unroll
      for (int s = 0; s < 2; ++s) {
        short8v vf = *reinterpret_cast<const short8v*>(&vr[((s * 4 + g) ^ swz) * 8]);
        oacc[d0] = __builtin_amdgcn_mfma_f32_16x16x32_bf16(vf, pfr[s], oacc[d0], 0, 0, 0);
      }
    }
    __builtin_amdgcn_s_setprio(0);

    asm volatile("" ::: "memory");
    __builtin_amdgcn_s_barrier();
    asm volatile("" ::: "memory");
    mw_cur = mw_nxt;
    cur ^= 1;
  }

  // epilogue: reduce the per-lane l_run partials across the 4 g-lanes of this q
  l_run += __shfl_xor(l_run, 16);
  l_run += __shfl_xor(l_run, 32);
  float inv = 1.f / l_run;
#pragma unroll
  for (int d0 = 0; d0 < 4; ++d0) {
    ushort4 o;
    o.x = f2bf(oacc[d0][0] * inv);
    o.y = f2bf(oacc[d0][1] * inv);
    o.z = f2bf(oacc[d0][2] * inv);
    o.w = f2bf(oacc[d0][3] * inv);
    *reinterpret_cast<ushort4*>(&attn[((long)b * S_ + q0) * D_ + h * HD_ + d0 * 16 + g * 4]) = o;
  }
}

// ---------------- launch (round-16 order: pack_mask AFTER gemm_qkv -- MBITS overlays XK) ----------------
extern "C" void kernel_launch(void* const* d_in, const int* in_sizes, int n_in,
                              void* d_out, int out_size, void* d_ws, size_t ws_size,
                              hipStream_t stream) {
  const float* query = (const float*)d_in[0];
  const float* key   = (const float*)d_in[1];
  const float* value = (const float*)d_in[2];
  const float* mask  = (const float*)d_in[3];
  const float* Wq = (const float*)d_in[4];
  const float* bq = (const float*)d_in[5];
  const float* Wk = (const float*)d_in[6];
  const float* bk = (const float*)d_in[7];
  const float* Wv = (const float*)d_in[8];
  const float* bv = (const float*)d_in[9];
  const float* Wo = (const float*)d_in[10];
  const float* bo = (const float*)d_in[11];

  char* ws = (char*)d_ws;
  unsigned short* XQ  = (unsigned short*)(ws);
  unsigned short* XK  = (unsigned short*)(ws + (16ull << 20));
  unsigned short* XV  = (unsigned short*)(ws + (32ull << 20));
  unsigned short* WQT = (unsigned short*)(ws + (48ull << 20));
  unsigned short* WKT = (unsigned short*)(ws + (50ull << 20));
  unsigned short* WVT = (unsigned short*)(ws + (52ull << 20));
  unsigned short* WOT = (unsigned short*)(ws + (54ull << 20));
  unsigned short* QB  = (unsigned short*)(ws + (56ull << 20));
  unsigned short* KB  = (unsigned short*)(ws + (72ull << 20));
  unsigned short* VT  = (unsigned short*)(ws + (88ull << 20));
  unsigned long long* MBITS = (unsigned long long*)(ws + (16ull << 20));  // overlays XK (dead post-gemm_qkv)
  unsigned short* ATTN = XQ;                                              // overlays XQ (dead post-gemm_qkv)

  const int n4 = M_ * D_ / 4;
  dim3 cg(2048, 1, 3);
  cast3_bf16_kernel<<<cg, 256, 0, stream>>>(query, key, value, XQ, XK, XV, n4);

  dim3 tg(D_ / 32, D_ / 32, 4), tb(32, 8);
  transpose_cast4_kernel<<<tg, tb, 0, stream>>>(Wq, Wk, Wv, Wo, WQT, WKT, WVT, WOT, D_);

  // Q prescale: 1/sqrt(HD) * log2(e) so softmax runs in exp2 domain
  dim3 gq(M_ / 128, D_ / 128, 3);
  gemm_qkv_kernel<<<gq, 256, 0, stream>>>(XQ, XK, XV, WQT, WKT, WVT, bq, bk, bv,
                                          QB, KB, VT, 0.18033688011112042f);

  pack_mask_kernel<<<2048, 256, 0, stream>>>(mask, MBITS, B_ * S_ * S_ / 64);

  dim3 ag(S_ / 64, B_ * H_);
  attn_kernel<<<ag, 256, 0, stream>>>(QB, KB, VT, MBITS, ATTN);

  dim3 gg(M_ / 128, D_ / 128);
  gemm_out_kernel<<<gg, 256, 0, stream>>>(ATTN, WOT, bo, (float*)d_out);
}